// Round 13
// baseline (644.338 us; speedup 1.0000x reference)
//
#include <hip/hip_runtime.h>
#include <hip/hip_bf16.h>

// GAT 3-layer forward. N=50000, E=1.6M, H=4, D=32, C=47.
// Round 13: HEAD-PHASED gather. fs/hbuf/el/er stored head-major; agg grids
// ordered head-major (head = blockIdx/(N/4)) so each phase's table slice
// (3.2-4.8 MB) is per-XCD L2-resident -> gather L2 misses collapse to
// compulsory (predicted agg2 FETCH 281 -> ~40-90 MB).
//
// ws: fs[N*192 bf16] hb16[N*128 bf16] xpad[N*128 bf16] out2[N*192 bf16]
//     el/er[N*4 f32] rowptr deg col16 slot16 bsum boff flag  => ~72 MB.

using bf16 = __hip_bfloat16;
typedef __attribute__((ext_vector_type(8))) short short8;
typedef __attribute__((ext_vector_type(4))) float floatx4;

static constexpr int NN = 50000;
static constexpr int H  = 4;

__device__ __forceinline__ float b2f(bf16 x) { return __bfloat162float(x); }
__device__ __forceinline__ float ldx(const void* p, size_t i, bool bf) {
    return bf ? __bfloat162float(((const bf16*)p)[i]) : ((const float*)p)[i];
}
__device__ __forceinline__ unsigned short f2b_bits(float v) {
    bf16 h = __float2bfloat16(v);
    return *reinterpret_cast<unsigned short*>(&h);
}
__device__ __forceinline__ unsigned short w_bits(const void* p, size_t i, bool bf) {
    if (bf) return ((const unsigned short*)p)[i];
    return f2b_bits(((const float*)p)[i]);
}
__device__ __forceinline__ float bl(unsigned u) { return __uint_as_float(u << 16); }
__device__ __forceinline__ float bh(unsigned u) { return __uint_as_float(u & 0xFFFF0000u); }

// ---------- dtype detection (bf16 vs fp32) ----------
__global__ void detect_k(const void* __restrict__ x, int* __restrict__ flag) {
    __shared__ int cnt;
    if (threadIdx.x == 0) cnt = 0;
    __syncthreads();
    const unsigned short* u = (const unsigned short*)x;
    unsigned short b = u[threadIdx.x * 2];
    int e = (b >> 7) & 0xFF;
    if (e >= 0x70 && e <= 0x8F) atomicAdd(&cnt, 1);
    __syncthreads();
    if (threadIdx.x == 0) *flag = (cnt > 128) ? 1 : 0;
}

// ---------- pad/convert x[N,100] -> bf16 [N,128] ----------
__global__ void xpad_k(const void* __restrict__ x, bf16* __restrict__ xp,
                       const int* __restrict__ flag, int total) {
    int i = blockIdx.x * 256 + threadIdx.x;
    if (i >= total) return;
    const bool bf = (*flag != 0);
    int n = i >> 7, k = i & 127;
    float v = (k < 100) ? ldx(x, (size_t)n * 100 + k, bf) : 0.f;
    xp[i] = __float2bfloat16(v);
}

// ---------- CSR build (by dst) ----------
__global__ void deg_k(const int* __restrict__ dst, int* __restrict__ deg,
                      unsigned short* __restrict__ slot16, int E) {
    int e = blockIdx.x * 256 + threadIdx.x;
    if (e >= E) return;
    int p = atomicAdd(&deg[dst[e]], 1);
    slot16[e] = (unsigned short)p;
}

__global__ void scan1_k(const int* __restrict__ deg, int* __restrict__ rowptr,
                        int* __restrict__ bsum, int N) {
    __shared__ int buf[256];
    int tid = threadIdx.x, i = blockIdx.x * 256 + tid;
    int v = (i < N) ? deg[i] : 0;
    buf[tid] = v;
    __syncthreads();
    for (int off = 1; off < 256; off <<= 1) {
        int t = (tid >= off) ? buf[tid - off] : 0;
        __syncthreads();
        buf[tid] += t;
        __syncthreads();
    }
    if (i < N) rowptr[i] = buf[tid] - v;
    if (tid == 255) bsum[blockIdx.x] = buf[255];
}

__global__ void scan2_k(const int* __restrict__ bsum, int* __restrict__ boff, int nb) {
    __shared__ int buf[256];
    int tid = threadIdx.x;
    int v = (tid < nb) ? bsum[tid] : 0;
    buf[tid] = v;
    __syncthreads();
    for (int off = 1; off < 256; off <<= 1) {
        int t = (tid >= off) ? buf[tid - off] : 0;
        __syncthreads();
        buf[tid] += t;
        __syncthreads();
    }
    if (tid < nb) boff[tid] = buf[tid] - v;
}

__global__ void scan3_k(int* __restrict__ rowptr, const int* __restrict__ boff,
                        int N, int E) {
    int i = blockIdx.x * 256 + threadIdx.x;
    if (i < N) rowptr[i] += boff[blockIdx.x];
    if (i == 0) rowptr[N] = E;
}

__global__ void fill_k(const int* __restrict__ src, const int* __restrict__ dst,
                       const int* __restrict__ rowptr,
                       const unsigned short* __restrict__ slot16,
                       unsigned short* __restrict__ col16, int E) {
    int e = blockIdx.x * 256 + threadIdx.x;
    if (e >= E) return;
    int d = dst[e];
    col16[rowptr[d] + slot16[e]] = (unsigned short)src[e];
}

// ---------- MFMA GEMM (128 nodes/block) + fused el/er epilogue ----------
// fs written HEAD-MAJOR: fs[h][node][HS] = fs[((size_t)h*N + node)*HS + j].
// el/er head-major: el[h*N + node]. IN_HM: input is head-major [4][N][32]
// (chunk k-slice == head slice); else flat bf16 [N,128].
template <int KW, int M, int S, int HS, int HW, bool IN_HM>
__global__ void __launch_bounds__(256) gemm_k(const bf16* __restrict__ in,
                                              const void* __restrict__ W,
                                              const void* __restrict__ al,
                                              const void* __restrict__ ar,
                                              bf16* __restrict__ fs,
                                              float* __restrict__ el,
                                              float* __restrict__ er,
                                              const int* __restrict__ flag, int N) {
    constexpr int CT  = S / 16;
    constexpr int WST = 136;
    __shared__ short wlds[S * WST];
    const bool bf = (*flag != 0);
    const int tid = threadIdx.x;

    for (int idx = tid; idx < 64 * S; idx += 256) {
        int k2 = idx / S, p = idx % S;
        int j = p % HS, h = p / HS;
        int c = h * HW + j;
        bool valid = (j < HW);
        int k0 = 2 * k2;
        unsigned short u0 = (valid && k0 < KW)     ? w_bits(W, (size_t)k0 * M + c, bf)       : 0;
        unsigned short u1 = (valid && k0 + 1 < KW) ? w_bits(W, (size_t)(k0 + 1) * M + c, bf) : 0;
        *(unsigned*)&wlds[p * WST + 2 * k2] = (unsigned)u0 | ((unsigned)u1 << 16);
    }
    __syncthreads();

    const int wave = tid >> 6, lane = tid & 63;
    const int q = lane >> 4, l16 = lane & 15;
    const int base = blockIdx.x * 128;

    floatx4 acc[2][CT] = {};

#pragma unroll
    for (int chunk = 0; chunk < 4; ++chunk) {
        const int kb = chunk * 32 + q * 8;
        short8 a0 = {}, a1 = {};
        const int n0 = base + wave * 16 + l16;
        const int n1 = n0 + 64;
        if (IN_HM) {
            const bf16* sl = in + (size_t)chunk * N * 32 + q * 8;
            if (n0 < N) a0 = *(const short8*)(sl + (size_t)n0 * 32);
            if (n1 < N) a1 = *(const short8*)(sl + (size_t)n1 * 32);
        } else {
            if (n0 < N) a0 = *(const short8*)(in + (size_t)n0 * 128 + kb);
            if (n1 < N) a1 = *(const short8*)(in + (size_t)n1 * 128 + kb);
        }
#pragma unroll
        for (int ct = 0; ct < CT; ++ct) {
            const int p = ct * 16 + l16;
            short8 b = *(const short8*)&wlds[p * WST + kb];
            acc[0][ct] = __builtin_amdgcn_mfma_f32_16x16x32_bf16(a0, b, acc[0][ct], 0, 0, 0);
            acc[1][ct] = __builtin_amdgcn_mfma_f32_16x16x32_bf16(a1, b, acc[1][ct], 0, 0, 0);
        }
    }

    // ---- store fs head-major ----
#pragma unroll
    for (int rt = 0; rt < 2; ++rt) {
        const int tb = base + rt * 64 + wave * 16;
#pragma unroll
        for (int ct = 0; ct < CT; ++ct) {
            const int p = ct * 16 + l16;
            const int h = p / HS, j = p % HS;
            bf16* dstp = fs + ((size_t)h * N) * HS + j;
#pragma unroll
            for (int r = 0; r < 4; ++r) {
                int node = tb + q * 4 + r;
                if (node < N) dstp[(size_t)node * HS] = __float2bfloat16(acc[rt][ct][r]);
            }
        }
    }

    // ---- fused el/er (head-major out) ----
    float* red = (float*)wlds;
#pragma unroll
    for (int rt = 0; rt < 2; ++rt) {
        __syncthreads();
        float elp[4][4] = {}, erp[4][4] = {};
#pragma unroll
        for (int ct = 0; ct < CT; ++ct) {
            const int p = ct * 16 + l16;
            const int j = p % HS, h = p / HS;
            const bool valid = (j < HW);
            float alc = valid ? ldx(al, h * HW + j, bf) : 0.f;
            float arc = valid ? ldx(ar, h * HW + j, bf) : 0.f;
#pragma unroll
            for (int r = 0; r < 4; ++r) {
                float v = acc[rt][ct][r];
#pragma unroll
                for (int h2 = 0; h2 < 4; ++h2) {
                    elp[r][h2] += (h == h2) ? v * alc : 0.f;
                    erp[r][h2] += (h == h2) ? v * arc : 0.f;
                }
            }
        }
#pragma unroll
        for (int r = 0; r < 4; ++r)
#pragma unroll
            for (int h2 = 0; h2 < 4; ++h2) {
                int slot = (wave * 128) + (q * 32) + (r * 8) + (h2 * 2);
                red[slot * 16 + l16] = elp[r][h2];
                red[(slot + 1) * 16 + l16] = erp[r][h2];
            }
        __syncthreads();
#pragma unroll
        for (int pass = 0; pass < 2; ++pass) {
            int slot = tid + pass * 256;
            float sum = 0.f;
#pragma unroll
            for (int j = 0; j < 16; ++j) sum += red[slot * 16 + j];
            int which = slot & 1;
            int h2 = (slot >> 1) & 3;
            int r  = (slot >> 3) & 3;
            int qq = (slot >> 5) & 3;
            int wv = slot >> 7;
            int node = base + rt * 64 + wv * 16 + qq * 4 + r;
            if (node < N) {
                if (which == 0) el[(size_t)h2 * N + node] = sum;
                else            er[(size_t)h2 * N + node] = sum;
            }
        }
    }
}

// ---------- head-phased agg, layers 0/1 (HS=32) ----------
// grid = 4*ceil(N/4); head = blockIdx/per (phases time-separated).
// Wave per dst: chunk of 64 edges staged by 64 lanes (1 exp each), gather
// 16 edges x 4 lanes x 16B, lane loops k=0..3 (4 loads in flight). Zero
// barriers (wave-private LDS). out head-major [4][N][32] bf16.
template <bool RELU>
__global__ void __launch_bounds__(256) agg01h_k(const float* __restrict__ el,
                                                const float* __restrict__ er,
                                                const bf16* __restrict__ fs,
                                                const int* __restrict__ rowptr,
                                                const unsigned short* __restrict__ col,
                                                bf16* __restrict__ out, int N) {
    const int per = (N + 3) / 4;
    const int h = blockIdx.x / per;
    const int blk = blockIdx.x - h * per;
    const int wave = threadIdx.x >> 6, lane = threadIdx.x & 63;
    const int d = blk * 4 + wave;
    __shared__ float wlds[4][64];
    __shared__ int   scol[4][64];
    if (d >= N) return;
    const int rs = rowptr[d], re = rowptr[d + 1];
    const int lg = lane & 3;
    const int c0 = lg * 8;
    bf16* orow = out + ((size_t)h * N + d) * 32 + c0;

    if (re == rs) {
        if (lane < 4) *(uint4*)orow = make_uint4(0, 0, 0, 0);
        return;
    }

    const float er_d = er[(size_t)h * N + d];
    const bf16* fsl = fs + (size_t)h * N * 32;
    const float* ell = el + (size_t)h * N;

    const int eb = lane >> 2;
    float acc[8] = {0, 0, 0, 0, 0, 0, 0, 0};
    float swp = 0.f;

    for (int cs = rs; cs < re; cs += 64) {
        int ne = min(64, re - cs);
        if (lane < ne) {
            int s = (int)col[cs + lane];
            scol[wave][lane] = s;
            float x = ell[s] + er_d;
            x = x >= 0.f ? x : 0.2f * x;
            float w = __expf(x);
            wlds[wave][lane] = w;
            swp += w;
        }
#pragma unroll
        for (int k = 0; k < 4; ++k) {
            int e = eb + k * 16;
            if (e < ne) {
                int s = scol[wave][e];
                float w = wlds[wave][e];
                uint4 u = *(const uint4*)(fsl + (size_t)s * 32 + c0);
                acc[0] += w * bl(u.x); acc[1] += w * bh(u.x);
                acc[2] += w * bl(u.y); acc[3] += w * bh(u.y);
                acc[4] += w * bl(u.z); acc[5] += w * bh(u.z);
                acc[6] += w * bl(u.w); acc[7] += w * bh(u.w);
            }
        }
    }

    // sum over edge-owner lanes (bits 2..5)
#pragma unroll
    for (int k = 0; k < 8; ++k) {
        acc[k] += __shfl_xor(acc[k], 4);
        acc[k] += __shfl_xor(acc[k], 8);
        acc[k] += __shfl_xor(acc[k], 16);
        acc[k] += __shfl_xor(acc[k], 32);
    }
    // full weight sum
#pragma unroll
    for (int off = 1; off < 64; off <<= 1) swp += __shfl_xor(swp, off);

    if (lane < 4) {
        float inv = 1.0f / swp;
        float v[8];
#pragma unroll
        for (int k = 0; k < 8; ++k) {
            v[k] = acc[k] * inv;
            if (RELU) v[k] = fmaxf(v[k], 0.f);
        }
        uint4 o;
        o.x = (unsigned)f2b_bits(v[0]) | ((unsigned)f2b_bits(v[1]) << 16);
        o.y = (unsigned)f2b_bits(v[2]) | ((unsigned)f2b_bits(v[3]) << 16);
        o.z = (unsigned)f2b_bits(v[4]) | ((unsigned)f2b_bits(v[5]) << 16);
        o.w = (unsigned)f2b_bits(v[6]) | ((unsigned)f2b_bits(v[7]) << 16);
        *(uint4*)orow = o;
    }
}

// ---------- head-phased agg, layer 2 (HS=48) -> out2 head-major bf16 ----------
// Wave per dst; 6 lanes/edge (48 cols), 10 edges in flight (lanes 0..59),
// lane loops k=0..6. Wave-private LDS reduce for the stride-6 groups.
__global__ void __launch_bounds__(256) agg2h_k(const float* __restrict__ el,
                                               const float* __restrict__ er,
                                               const bf16* __restrict__ fs,
                                               const int* __restrict__ rowptr,
                                               const unsigned short* __restrict__ col,
                                               bf16* __restrict__ out2, int N) {
    const int per = (N + 3) / 4;
    const int h = blockIdx.x / per;
    const int blk = blockIdx.x - h * per;
    const int wave = threadIdx.x >> 6, lane = threadIdx.x & 63;
    const int d = blk * 4 + wave;
    __shared__ float wlds[4][64];
    __shared__ int   scol[4][64];
    __shared__ float part[4][10][48];
    if (d >= N) return;
    const int rs = rowptr[d], re = rowptr[d + 1];
    bf16* orow = out2 + ((size_t)h * N + d) * 48;

    if (re == rs) {
        if (lane < 48) orow[lane] = __float2bfloat16(0.f);
        return;
    }

    const float er_d = er[(size_t)h * N + d];
    const bf16* fsl = fs + (size_t)h * N * 48;
    const float* ell = el + (size_t)h * N;

    const int l6 = lane / 6;            // edge slot 0..9 (lane<60)
    const int lg = lane - l6 * 6;
    const int c0 = lg * 8;
    const bool act = (lane < 60);

    float acc[8] = {0, 0, 0, 0, 0, 0, 0, 0};
    float swp = 0.f;

    for (int cs = rs; cs < re; cs += 64) {
        int ne = min(64, re - cs);
        if (lane < ne) {
            int s = (int)col[cs + lane];
            scol[wave][lane] = s;
            float x = ell[s] + er_d;
            x = x >= 0.f ? x : 0.2f * x;
            float w = __expf(x);
            wlds[wave][lane] = w;
            swp += w;
        }
#pragma unroll
        for (int k = 0; k < 7; ++k) {
            int e = l6 + k * 10;
            if (act && e < ne) {
                int s = scol[wave][e];
                float w = wlds[wave][e];
                uint4 u = *(const uint4*)(fsl + (size_t)s * 48 + c0);
                acc[0] += w * bl(u.x); acc[1] += w * bh(u.x);
                acc[2] += w * bl(u.y); acc[3] += w * bh(u.y);
                acc[4] += w * bl(u.z); acc[5] += w * bh(u.z);
                acc[6] += w * bl(u.w); acc[7] += w * bh(u.w);
            }
        }
    }

    // stride-6 groups: reduce via wave-private LDS
    if (act) {
        *(float4*)&part[wave][l6][c0]     = make_float4(acc[0], acc[1], acc[2], acc[3]);
        *(float4*)&part[wave][l6][c0 + 4] = make_float4(acc[4], acc[5], acc[6], acc[7]);
    }
    // full weight sum
#pragma unroll
    for (int off = 1; off < 64; off <<= 1) swp += __shfl_xor(swp, off);

    if (lane < 48) {
        float v = 0.f;
#pragma unroll
        for (int i = 0; i < 10; ++i) v += part[wave][i][lane];
        orow[lane] = __float2bfloat16(v / swp);
    }
}

// ---------- head-mean + log_softmax from head-major out2 ----------
__global__ void final_k(const bf16* __restrict__ out2, void* __restrict__ out,
                        const int* __restrict__ flag, int N) {
    int n = blockIdx.x;
    int c = threadIdx.x;
    const bool bf = (*flag != 0);
    float val = 0.f, vm = -INFINITY;
    if (c < 47) {
        val = 0.25f * (b2f(out2[((size_t)0 * N + n) * 48 + c]) +
                       b2f(out2[((size_t)1 * N + n) * 48 + c]) +
                       b2f(out2[((size_t)2 * N + n) * 48 + c]) +
                       b2f(out2[((size_t)3 * N + n) * 48 + c]));
        vm = val;
    }
    float m = vm;
#pragma unroll
    for (int off = 32; off >= 1; off >>= 1) m = fmaxf(m, __shfl_xor(m, off));
    float ex = (c < 47) ? __expf(val - m) : 0.f;
    float s = ex;
#pragma unroll
    for (int off = 32; off >= 1; off >>= 1) s += __shfl_xor(s, off);
    if (c < 47) {
        float r = val - m - logf(s);
        if (bf) ((bf16*)out)[(size_t)n * 47 + c] = __float2bfloat16(r);
        else    ((float*)out)[(size_t)n * 47 + c] = r;
    }
}

extern "C" void kernel_launch(void* const* d_in, const int* in_sizes, int n_in,
                              void* d_out, int out_size, void* d_ws, size_t ws_size,
                              hipStream_t stream) {
    const void* x   = d_in[0];
    const void* W0  = d_in[1];
    const void* al0 = d_in[2];
    const void* ar0 = d_in[3];
    const void* W1  = d_in[4];
    const void* al1 = d_in[5];
    const void* ar1 = d_in[6];
    const void* W2  = d_in[7];
    const void* al2 = d_in[8];
    const void* ar2 = d_in[9];
    const int* src  = (const int*)d_in[10];
    const int* dst  = (const int*)d_in[11];
    const int E = in_sizes[10];
    const int N = NN;

    bf16* fs    = (bf16*)d_ws;                      // N*192 bf16 (head-major)
    bf16* hb16  = fs + (size_t)N * 192;             // N*128 bf16 (head-major)
    bf16* xpad  = hb16 + (size_t)N * 128;           // N*128 bf16 (flat)
    bf16* out2  = xpad + (size_t)N * 128;           // N*192 bf16 (head-major)
    float* el   = (float*)(out2 + (size_t)N * 192); // 4*N (head-major)
    float* er   = el + (size_t)N * H;               // 4*N
    int* rowptr = (int*)(er + (size_t)N * H);       // N+1
    int* deg    = rowptr + (N + 1);                 // N
    unsigned short* col16  = (unsigned short*)(deg + N);   // E u16
    unsigned short* slot16 = col16 + E;                    // E u16
    int* bsum   = (int*)(slot16 + E);               // 256
    int* boff   = bsum + 256;                       // 256
    int* flag   = boff + 256;                       // 1

    const int gN  = (N + 255) / 256;                // 196 blocks
    const int gE  = (E + 255) / 256;
    const int gG  = (N + 127) / 128;                // 391 gemm blocks
    const int gA  = 4 * ((N + 3) / 4);              // 50000 head-phased blocks

    detect_k<<<1, 256, 0, stream>>>(x, flag);
    xpad_k<<<(N * 128 + 255) / 256, 256, 0, stream>>>(x, xpad, flag, N * 128);

    // CSR build (graph identical for all 3 layers)
    hipMemsetAsync(deg, 0, (size_t)N * 4, stream);
    deg_k<<<gE, 256, 0, stream>>>(dst, deg, slot16, E);
    scan1_k<<<gN, 256, 0, stream>>>(deg, rowptr, bsum, N);
    scan2_k<<<1, 256, 0, stream>>>(bsum, boff, gN);
    scan3_k<<<gN, 256, 0, stream>>>(rowptr, boff, N, E);
    fill_k<<<gE, 256, 0, stream>>>(src, dst, rowptr, slot16, col16, E);

    // ---------------- Layer 0: W[100,128], HS=HW=32, flat input ----------
    gemm_k<100, 128, 128, 32, 32, false><<<gG, 256, 0, stream>>>(
        xpad, W0, al0, ar0, fs, el, er, flag, N);
    agg01h_k<true><<<gA, 256, 0, stream>>>(el, er, fs, rowptr, col16, hb16, N);

    // ---------------- Layer 1: W[128,128], HS=HW=32, head-major input ----
    gemm_k<128, 128, 128, 32, 32, true><<<gG, 256, 0, stream>>>(
        hb16, W1, al1, ar1, fs, el, er, flag, N);
    agg01h_k<true><<<gA, 256, 0, stream>>>(el, er, fs, rowptr, col16, hb16, N);

    // ---------------- Layer 2: W[128,188], HS=48, HW=47, head-major in ---
    gemm_k<128, 188, 192, 48, 47, true><<<gG, 256, 0, stream>>>(
        hb16, W2, al2, ar2, fs, el, er, flag, N);
    agg2h_k<<<gA, 256, 0, stream>>>(el, er, fs, rowptr, col16, out2, N);

    final_k<<<N, 64, 0, stream>>>(out2, d_out, flag, N);
}

// Round 14
// 562.380 us; speedup vs baseline: 1.1457x; 1.1457x over previous
//
#include <hip/hip_runtime.h>
#include <hip/hip_bf16.h>

// GAT 3-layer forward. N=50000, E=1.6M, H=4, D=32, C=47.
// Round 14: revert to R12 (R13's head-phasing cut FETCH 281->191 MB but
// halved gather MLP -> net loss; lesson: in-flight loads/lane dominate).
// Only change vs R12: agg01 stages 64 edges/chunk (was 16) -> 1 staging
// turnaround per mean-degree row instead of 2.
//
// ws: fs[N*192 bf16] hb16[N*128 bf16] xpad[N*128 bf16] el/er[N*4 f32]
//     rowptr[N+1] deg[N] col16[E u16] slot16[E u16] bsum boff flag.

using bf16 = __hip_bfloat16;
typedef __attribute__((ext_vector_type(8))) short short8;
typedef __attribute__((ext_vector_type(4))) float floatx4;

static constexpr int NN = 50000;
static constexpr int H  = 4;

__device__ __forceinline__ float b2f(bf16 x) { return __bfloat162float(x); }
__device__ __forceinline__ float ldx(const void* p, size_t i, bool bf) {
    return bf ? __bfloat162float(((const bf16*)p)[i]) : ((const float*)p)[i];
}
__device__ __forceinline__ unsigned short f2b_bits(float v) {
    bf16 h = __float2bfloat16(v);
    return *reinterpret_cast<unsigned short*>(&h);
}
__device__ __forceinline__ unsigned short w_bits(const void* p, size_t i, bool bf) {
    if (bf) return ((const unsigned short*)p)[i];
    return f2b_bits(((const float*)p)[i]);
}
__device__ __forceinline__ float bl(unsigned u) { return __uint_as_float(u << 16); }
__device__ __forceinline__ float bh(unsigned u) { return __uint_as_float(u & 0xFFFF0000u); }

// ---------- dtype detection (bf16 vs fp32) ----------
__global__ void detect_k(const void* __restrict__ x, int* __restrict__ flag) {
    __shared__ int cnt;
    if (threadIdx.x == 0) cnt = 0;
    __syncthreads();
    const unsigned short* u = (const unsigned short*)x;
    unsigned short b = u[threadIdx.x * 2];
    int e = (b >> 7) & 0xFF;
    if (e >= 0x70 && e <= 0x8F) atomicAdd(&cnt, 1);
    __syncthreads();
    if (threadIdx.x == 0) *flag = (cnt > 128) ? 1 : 0;
}

// ---------- pad/convert x[N,100] -> bf16 [N,128] ----------
__global__ void xpad_k(const void* __restrict__ x, bf16* __restrict__ xp,
                       const int* __restrict__ flag, int total) {
    int i = blockIdx.x * 256 + threadIdx.x;
    if (i >= total) return;
    const bool bf = (*flag != 0);
    int n = i >> 7, k = i & 127;
    float v = (k < 100) ? ldx(x, (size_t)n * 100 + k, bf) : 0.f;
    xp[i] = __float2bfloat16(v);
}

// ---------- CSR build (by dst); deg pass also captures per-edge slot ----------
__global__ void deg_k(const int* __restrict__ dst, int* __restrict__ deg,
                      unsigned short* __restrict__ slot16, int E) {
    int e = blockIdx.x * 256 + threadIdx.x;
    if (e >= E) return;
    int p = atomicAdd(&deg[dst[e]], 1);
    slot16[e] = (unsigned short)p;
}

__global__ void scan1_k(const int* __restrict__ deg, int* __restrict__ rowptr,
                        int* __restrict__ bsum, int N) {
    __shared__ int buf[256];
    int tid = threadIdx.x, i = blockIdx.x * 256 + tid;
    int v = (i < N) ? deg[i] : 0;
    buf[tid] = v;
    __syncthreads();
    for (int off = 1; off < 256; off <<= 1) {
        int t = (tid >= off) ? buf[tid - off] : 0;
        __syncthreads();
        buf[tid] += t;
        __syncthreads();
    }
    if (i < N) rowptr[i] = buf[tid] - v;
    if (tid == 255) bsum[blockIdx.x] = buf[255];
}

__global__ void scan2_k(const int* __restrict__ bsum, int* __restrict__ boff, int nb) {
    __shared__ int buf[256];
    int tid = threadIdx.x;
    int v = (tid < nb) ? bsum[tid] : 0;
    buf[tid] = v;
    __syncthreads();
    for (int off = 1; off < 256; off <<= 1) {
        int t = (tid >= off) ? buf[tid - off] : 0;
        __syncthreads();
        buf[tid] += t;
        __syncthreads();
    }
    if (tid < nb) boff[tid] = buf[tid] - v;
}

__global__ void scan3_k(int* __restrict__ rowptr, const int* __restrict__ boff,
                        int N, int E) {
    int i = blockIdx.x * 256 + threadIdx.x;
    if (i < N) rowptr[i] += boff[blockIdx.x];
    if (i == 0) rowptr[N] = E;
}

// atomic-free fill: slot from deg pass, ushort scatter
__global__ void fill_k(const int* __restrict__ src, const int* __restrict__ dst,
                       const int* __restrict__ rowptr,
                       const unsigned short* __restrict__ slot16,
                       unsigned short* __restrict__ col16, int E) {
    int e = blockIdx.x * 256 + threadIdx.x;
    if (e >= E) return;
    int d = dst[e];
    col16[rowptr[d] + slot16[e]] = (unsigned short)src[e];
}

// ---------- MFMA GEMM (128 nodes/block) + fused el/er epilogue ----------
template <int KW, int M, int S, int HS, int HW>
__global__ void __launch_bounds__(256) gemm_k(const bf16* __restrict__ in,
                                              const void* __restrict__ W,
                                              const void* __restrict__ al,
                                              const void* __restrict__ ar,
                                              bf16* __restrict__ fs,
                                              float* __restrict__ el,
                                              float* __restrict__ er,
                                              const int* __restrict__ flag, int N) {
    constexpr int CT  = S / 16;
    constexpr int WST = 136;
    __shared__ short wlds[S * WST];
    const bool bf = (*flag != 0);
    const int tid = threadIdx.x;

    for (int idx = tid; idx < 64 * S; idx += 256) {
        int k2 = idx / S, p = idx % S;
        int j = p % HS, h = p / HS;
        int c = h * HW + j;
        bool valid = (j < HW);
        int k0 = 2 * k2;
        unsigned short u0 = (valid && k0 < KW)     ? w_bits(W, (size_t)k0 * M + c, bf)       : 0;
        unsigned short u1 = (valid && k0 + 1 < KW) ? w_bits(W, (size_t)(k0 + 1) * M + c, bf) : 0;
        *(unsigned*)&wlds[p * WST + 2 * k2] = (unsigned)u0 | ((unsigned)u1 << 16);
    }
    __syncthreads();

    const int wave = tid >> 6, lane = tid & 63;
    const int q = lane >> 4, l16 = lane & 15;
    const int base = blockIdx.x * 128;

    floatx4 acc[2][CT] = {};

#pragma unroll
    for (int chunk = 0; chunk < 4; ++chunk) {
        const int kb = chunk * 32 + q * 8;
        short8 a0 = {}, a1 = {};
        const int n0 = base + wave * 16 + l16;
        const int n1 = n0 + 64;
        if (n0 < N) a0 = *(const short8*)(in + (size_t)n0 * 128 + kb);
        if (n1 < N) a1 = *(const short8*)(in + (size_t)n1 * 128 + kb);
#pragma unroll
        for (int ct = 0; ct < CT; ++ct) {
            const int p = ct * 16 + l16;
            short8 b = *(const short8*)&wlds[p * WST + kb];
            acc[0][ct] = __builtin_amdgcn_mfma_f32_16x16x32_bf16(a0, b, acc[0][ct], 0, 0, 0);
            acc[1][ct] = __builtin_amdgcn_mfma_f32_16x16x32_bf16(a1, b, acc[1][ct], 0, 0, 0);
        }
    }

#pragma unroll
    for (int rt = 0; rt < 2; ++rt) {
        const int tb = base + rt * 64 + wave * 16;
#pragma unroll
        for (int ct = 0; ct < CT; ++ct) {
            const int p = ct * 16 + l16;
#pragma unroll
            for (int r = 0; r < 4; ++r) {
                int node = tb + q * 4 + r;
                if (node < N) fs[(size_t)node * S + p] = __float2bfloat16(acc[rt][ct][r]);
            }
        }
    }

    float* red = (float*)wlds;
#pragma unroll
    for (int rt = 0; rt < 2; ++rt) {
        __syncthreads();
        float elp[4][4] = {}, erp[4][4] = {};
#pragma unroll
        for (int ct = 0; ct < CT; ++ct) {
            const int p = ct * 16 + l16;
            const int j = p % HS, h = p / HS;
            const bool valid = (j < HW);
            float alc = valid ? ldx(al, h * HW + j, bf) : 0.f;
            float arc = valid ? ldx(ar, h * HW + j, bf) : 0.f;
#pragma unroll
            for (int r = 0; r < 4; ++r) {
                float v = acc[rt][ct][r];
#pragma unroll
                for (int h2 = 0; h2 < 4; ++h2) {
                    elp[r][h2] += (h == h2) ? v * alc : 0.f;
                    erp[r][h2] += (h == h2) ? v * arc : 0.f;
                }
            }
        }
#pragma unroll
        for (int r = 0; r < 4; ++r)
#pragma unroll
            for (int h2 = 0; h2 < 4; ++h2) {
                int slot = (wave * 128) + (q * 32) + (r * 8) + (h2 * 2);
                red[slot * 16 + l16] = elp[r][h2];
                red[(slot + 1) * 16 + l16] = erp[r][h2];
            }
        __syncthreads();
#pragma unroll
        for (int pass = 0; pass < 2; ++pass) {
            int slot = tid + pass * 256;
            float sum = 0.f;
#pragma unroll
            for (int j = 0; j < 16; ++j) sum += red[slot * 16 + j];
            int which = slot & 1;
            int h2 = (slot >> 1) & 3;
            int r  = (slot >> 3) & 3;
            int qq = (slot >> 5) & 3;
            int wv = slot >> 7;
            int node = base + rt * 64 + wv * 16 + qq * 4 + r;
            if (node < N) {
                if (which == 0) el[(size_t)node * 4 + h2] = sum;
                else            er[(size_t)node * 4 + h2] = sum;
            }
        }
    }
}

// ---------- wave-autonomous agg, layers 0/1 (S=128, HS=32) ----------
// One wave per dst; 64-edge staged chunks (4 stage sub-passes/lane), then
// barrier-free gather: 4 groups x 16 lanes x 16B, lane strides 4, unroll 4.
template <bool RELU>
__global__ void __launch_bounds__(256) agg01_k(const float* __restrict__ el,
                                               const float* __restrict__ er,
                                               const bf16* __restrict__ fs,
                                               const int* __restrict__ rowptr,
                                               const unsigned short* __restrict__ col,
                                               bf16* __restrict__ out, int N) {
    const int wave = threadIdx.x >> 6, lane = threadIdx.x & 63;
    const int d = blockIdx.x * 4 + wave;
    __shared__ float wrow[4][64][4];
    __shared__ int   scol[4][64];
    if (d >= N) return;
    const int rs = rowptr[d], re = rowptr[d + 1];
    const int g = lane >> 4, lg = lane & 15;
    const int c0 = lg * 8;

    if (re == rs) {
        if (g == 0) *(uint4*)(out + (size_t)d * 128 + c0) = make_uint4(0, 0, 0, 0);
        return;
    }

    float4 er4 = *(const float4*)(er + (size_t)d * 4);
    float er_d[4] = {er4.x, er4.y, er4.z, er4.w};

    const int eh = lane >> 2;               // staged edge slot (0..15) per sub-pass
    const int hh = lane & 3;                // staged head
    const int h0 = lg >> 2;                 // gather head (c0/32)

    float acc[8] = {0, 0, 0, 0, 0, 0, 0, 0};
    float swp = 0.f;

    for (int cs = rs; cs < re; cs += 64) {
        int ne = min(64, re - cs);
        // ---- stage up to 64 edges (4 sub-passes, one (edge,head) per lane) ----
#pragma unroll
        for (int t = 0; t < 4; ++t) {
            int j = eh + t * 16;
            if (j < ne) {
                int s = (int)col[cs + j];
                if (hh == 0) scol[wave][j] = s;
                float x = el[(size_t)s * 4 + hh] + er_d[hh];
                x = x >= 0.f ? x : 0.2f * x;
                float w = __expf(x);
                wrow[wave][j][hh] = w;
                swp += w;
            }
        }
        // ---- barrier-free gather (same-wave LDS dependency) ----
#pragma unroll 4
        for (int e = g; e < ne; e += 4) {
            int s = scol[wave][e];
            float w = wrow[wave][e][h0];
            uint4 u = *(const uint4*)(fs + (size_t)s * 128 + c0);
            acc[0] += w * bl(u.x); acc[1] += w * bh(u.x);
            acc[2] += w * bl(u.y); acc[3] += w * bh(u.y);
            acc[4] += w * bl(u.z); acc[5] += w * bh(u.z);
            acc[6] += w * bl(u.w); acc[7] += w * bh(u.w);
        }
    }

#pragma unroll
    for (int k = 0; k < 8; ++k) {
        acc[k] += __shfl_xor(acc[k], 16);
        acc[k] += __shfl_xor(acc[k], 32);
    }
#pragma unroll
    for (int off = 4; off < 64; off <<= 1) swp += __shfl_xor(swp, off);
    float sh = __shfl(swp, h0);

    if (g == 0) {
        float inv = 1.0f / sh;
        float v[8];
#pragma unroll
        for (int k = 0; k < 8; ++k) {
            v[k] = acc[k] * inv;
            if (RELU) v[k] = fmaxf(v[k], 0.f);
        }
        uint4 o;
        o.x = (unsigned)f2b_bits(v[0]) | ((unsigned)f2b_bits(v[1]) << 16);
        o.y = (unsigned)f2b_bits(v[2]) | ((unsigned)f2b_bits(v[3]) << 16);
        o.z = (unsigned)f2b_bits(v[4]) | ((unsigned)f2b_bits(v[5]) << 16);
        o.w = (unsigned)f2b_bits(v[6]) | ((unsigned)f2b_bits(v[7]) << 16);
        *(uint4*)(out + (size_t)d * 128 + c0) = o;
    }
}

// ---------- layer-2 agg + fused head-mean + log_softmax -> d_out ----------
__global__ void __launch_bounds__(192) agg2_k(const float* __restrict__ el,
                                              const float* __restrict__ er,
                                              const bf16* __restrict__ fs,
                                              const int* __restrict__ rowptr,
                                              const unsigned short* __restrict__ col,
                                              void* __restrict__ out,
                                              const int* __restrict__ flag) {
    constexpr int HS = 48, S = 192, LPG = 24, TPB = 192;
    constexpr int NG = TPB / LPG;       // 8
    constexpr int CH = TPB / 4;         // 48
    constexpr int NW = TPB / 64;        // 3
    const int d = blockIdx.x;
    const int tid = threadIdx.x;
    const bool bf = (*flag != 0);
    const int rs = rowptr[d], re = rowptr[d + 1];

    __shared__ float wrow[CH][4];
    __shared__ int scol_s[CH];
    __shared__ float part[NG][S];
    __shared__ float red2[NW][4];
    __shared__ float sh_s[4];
    __shared__ float vout[S];

    if (re == rs) {
        if (tid < 47) {
            float r = -logf(47.f);
            if (bf) ((bf16*)out)[(size_t)d * 47 + tid] = __float2bfloat16(r);
            else    ((float*)out)[(size_t)d * 47 + tid] = r;
        }
        return;
    }

    float4 er4 = *(const float4*)(er + (size_t)d * 4);
    float er_d[4] = {er4.x, er4.y, er4.z, er4.w};

    const int g  = tid / LPG;
    const int lg = tid % LPG;
    const int c0 = lg * 8;
    const int h0 = c0 / HS;

    float acc[8] = {0, 0, 0, 0, 0, 0, 0, 0};
    float swpart = 0.f;

    for (int cs = rs; cs < re; cs += CH) {
        int ne = min(CH, re - cs);
        if (tid < ne * 4) {
            int j = tid >> 2, h = tid & 3;
            int s = (int)col[cs + j];
            if (h == 0) scol_s[j] = s;
            float x = el[(size_t)s * 4 + h] + er_d[h];
            x = x >= 0.f ? x : 0.2f * x;
            float w = __expf(x);
            wrow[j][h] = w;
            swpart += w;
        }
        __syncthreads();
#pragma unroll 4
        for (int e = g; e < ne; e += NG) {
            int s = scol_s[e];
            uint4 u = *(const uint4*)(fs + (size_t)s * S + c0);
            float w = wrow[e][h0];
            acc[0] += w * bl(u.x); acc[1] += w * bh(u.x);
            acc[2] += w * bl(u.y); acc[3] += w * bh(u.y);
            acc[4] += w * bl(u.z); acc[5] += w * bh(u.z);
            acc[6] += w * bl(u.w); acc[7] += w * bh(u.w);
        }
        __syncthreads();
    }

    float sw = swpart;
#pragma unroll
    for (int off = 4; off < 64; off <<= 1) sw += __shfl_xor(sw, off);
    const int wave = tid >> 6, lane = tid & 63;
    if (lane < 4) red2[wave][lane] = sw;
#pragma unroll
    for (int k = 0; k < 8; ++k) part[g][c0 + k] = acc[k];
    __syncthreads();
    if (tid < 4) {
        float s = 0.f;
#pragma unroll
        for (int w = 0; w < NW; ++w) s += red2[w][tid];
        sh_s[tid] = s;
    }
    __syncthreads();

    if (tid < S / 4) {
        int c = tid * 4;
        float4 v = make_float4(0, 0, 0, 0);
#pragma unroll
        for (int gg = 0; gg < NG; ++gg) {
            v.x += part[gg][c + 0]; v.y += part[gg][c + 1];
            v.z += part[gg][c + 2]; v.w += part[gg][c + 3];
        }
        float is = 1.0f / sh_s[c / HS];
        vout[c + 0] = v.x * is; vout[c + 1] = v.y * is;
        vout[c + 2] = v.z * is; vout[c + 3] = v.w * is;
    }
    __syncthreads();

    if (tid < 64) {
        int c = tid;
        float val = 0.f, vm = -INFINITY;
        if (c < 47) {
            val = 0.25f * (vout[c] + vout[48 + c] + vout[96 + c] + vout[144 + c]);
            vm = val;
        }
        float m = vm;
#pragma unroll
        for (int off = 32; off >= 1; off >>= 1) m = fmaxf(m, __shfl_xor(m, off));
        float ex = (c < 47) ? __expf(val - m) : 0.f;
        float s = ex;
#pragma unroll
        for (int off = 32; off >= 1; off >>= 1) s += __shfl_xor(s, off);
        if (c < 47) {
            float r = val - m - logf(s);
            if (bf) ((bf16*)out)[(size_t)d * 47 + c] = __float2bfloat16(r);
            else    ((float*)out)[(size_t)d * 47 + c] = r;
        }
    }
}

extern "C" void kernel_launch(void* const* d_in, const int* in_sizes, int n_in,
                              void* d_out, int out_size, void* d_ws, size_t ws_size,
                              hipStream_t stream) {
    const void* x   = d_in[0];
    const void* W0  = d_in[1];
    const void* al0 = d_in[2];
    const void* ar0 = d_in[3];
    const void* W1  = d_in[4];
    const void* al1 = d_in[5];
    const void* ar1 = d_in[6];
    const void* W2  = d_in[7];
    const void* al2 = d_in[8];
    const void* ar2 = d_in[9];
    const int* src  = (const int*)d_in[10];
    const int* dst  = (const int*)d_in[11];
    const int E = in_sizes[10];
    const int N = NN;

    bf16* fs    = (bf16*)d_ws;                      // N*192 bf16
    bf16* hb16  = fs + (size_t)N * 192;             // N*128 bf16
    bf16* xpad  = hb16 + (size_t)N * 128;           // N*128 bf16
    float* el   = (float*)(xpad + (size_t)N * 128); // N*4
    float* er   = el + (size_t)N * H;               // N*4
    int* rowptr = (int*)(er + (size_t)N * H);       // N+1
    int* deg    = rowptr + (N + 1);                 // N
    unsigned short* col16  = (unsigned short*)(deg + N);   // E u16
    unsigned short* slot16 = col16 + E;                    // E u16
    int* bsum   = (int*)(slot16 + E);               // 256
    int* boff   = bsum + 256;                       // 256
    int* flag   = boff + 256;                       // 1

    const int gN  = (N + 255) / 256;                // 196 blocks
    const int gE  = (E + 255) / 256;
    const int gG  = (N + 127) / 128;                // 391 gemm blocks
    const int gA  = (N + 3) / 4;                    // 12500 agg01 blocks

    detect_k<<<1, 256, 0, stream>>>(x, flag);
    xpad_k<<<(N * 128 + 255) / 256, 256, 0, stream>>>(x, xpad, flag, N * 128);

    // CSR build (graph identical for all 3 layers)
    hipMemsetAsync(deg, 0, (size_t)N * 4, stream);
    deg_k<<<gE, 256, 0, stream>>>(dst, deg, slot16, E);
    scan1_k<<<gN, 256, 0, stream>>>(deg, rowptr, bsum, N);
    scan2_k<<<1, 256, 0, stream>>>(bsum, boff, gN);
    scan3_k<<<gN, 256, 0, stream>>>(rowptr, boff, N, E);
    fill_k<<<gE, 256, 0, stream>>>(src, dst, rowptr, slot16, col16, E);

    // ---------------- Layer 0: W[100,128], HS=HW=32 ----------------
    gemm_k<100, 128, 128, 32, 32><<<gG, 256, 0, stream>>>(
        xpad, W0, al0, ar0, fs, el, er, flag, N);
    agg01_k<true><<<gA, 256, 0, stream>>>(el, er, fs, rowptr, col16, hb16, N);

    // ---------------- Layer 1: W[128,128], HS=HW=32 ----------------
    gemm_k<128, 128, 128, 32, 32><<<gG, 256, 0, stream>>>(
        hb16, W1, al1, ar1, fs, el, er, flag, N);
    agg01_k<true><<<gA, 256, 0, stream>>>(el, er, fs, rowptr, col16, hb16, N);

    // ---------------- Layer 2: W[128,188], HS=48, HW=47 (head-padded) ------
    gemm_k<128, 188, 192, 48, 47><<<gG, 256, 0, stream>>>(
        hb16, W2, al2, ar2, fs, el, er, flag, N);
    agg2_k<<<N, 192, 0, stream>>>(el, er, fs, rowptr, col16, d_out, flag);
}

// Round 15
// 534.891 us; speedup vs baseline: 1.2046x; 1.0514x over previous
//
#include <hip/hip_runtime.h>
#include <hip/hip_bf16.h>

// GAT 3-layer forward. N=50000, E=1.6M, H=4, D=32, C=47.
// Round 15: exact revert of agg01_k to R12 (16-edge staged chunks, ONE
// stage sub-pass per lane). R14's 64-edge staging prepended a 4-deep serial
// latency chain per chunk -> +28us. Everything else identical to R12/R14.
//
// ws: fs[N*192 bf16] hb16[N*128 bf16] xpad[N*128 bf16] el/er[N*4 f32]
//     rowptr[N+1] deg[N] col16[E u16] slot16[E u16] bsum boff flag.

using bf16 = __hip_bfloat16;
typedef __attribute__((ext_vector_type(8))) short short8;
typedef __attribute__((ext_vector_type(4))) float floatx4;

static constexpr int NN = 50000;
static constexpr int H  = 4;

__device__ __forceinline__ float b2f(bf16 x) { return __bfloat162float(x); }
__device__ __forceinline__ float ldx(const void* p, size_t i, bool bf) {
    return bf ? __bfloat162float(((const bf16*)p)[i]) : ((const float*)p)[i];
}
__device__ __forceinline__ unsigned short f2b_bits(float v) {
    bf16 h = __float2bfloat16(v);
    return *reinterpret_cast<unsigned short*>(&h);
}
__device__ __forceinline__ unsigned short w_bits(const void* p, size_t i, bool bf) {
    if (bf) return ((const unsigned short*)p)[i];
    return f2b_bits(((const float*)p)[i]);
}
__device__ __forceinline__ float bl(unsigned u) { return __uint_as_float(u << 16); }
__device__ __forceinline__ float bh(unsigned u) { return __uint_as_float(u & 0xFFFF0000u); }

// ---------- dtype detection (bf16 vs fp32) ----------
__global__ void detect_k(const void* __restrict__ x, int* __restrict__ flag) {
    __shared__ int cnt;
    if (threadIdx.x == 0) cnt = 0;
    __syncthreads();
    const unsigned short* u = (const unsigned short*)x;
    unsigned short b = u[threadIdx.x * 2];
    int e = (b >> 7) & 0xFF;
    if (e >= 0x70 && e <= 0x8F) atomicAdd(&cnt, 1);
    __syncthreads();
    if (threadIdx.x == 0) *flag = (cnt > 128) ? 1 : 0;
}

// ---------- pad/convert x[N,100] -> bf16 [N,128] ----------
__global__ void xpad_k(const void* __restrict__ x, bf16* __restrict__ xp,
                       const int* __restrict__ flag, int total) {
    int i = blockIdx.x * 256 + threadIdx.x;
    if (i >= total) return;
    const bool bf = (*flag != 0);
    int n = i >> 7, k = i & 127;
    float v = (k < 100) ? ldx(x, (size_t)n * 100 + k, bf) : 0.f;
    xp[i] = __float2bfloat16(v);
}

// ---------- CSR build (by dst); deg pass also captures per-edge slot ----------
__global__ void deg_k(const int* __restrict__ dst, int* __restrict__ deg,
                      unsigned short* __restrict__ slot16, int E) {
    int e = blockIdx.x * 256 + threadIdx.x;
    if (e >= E) return;
    int p = atomicAdd(&deg[dst[e]], 1);
    slot16[e] = (unsigned short)p;
}

__global__ void scan1_k(const int* __restrict__ deg, int* __restrict__ rowptr,
                        int* __restrict__ bsum, int N) {
    __shared__ int buf[256];
    int tid = threadIdx.x, i = blockIdx.x * 256 + tid;
    int v = (i < N) ? deg[i] : 0;
    buf[tid] = v;
    __syncthreads();
    for (int off = 1; off < 256; off <<= 1) {
        int t = (tid >= off) ? buf[tid - off] : 0;
        __syncthreads();
        buf[tid] += t;
        __syncthreads();
    }
    if (i < N) rowptr[i] = buf[tid] - v;
    if (tid == 255) bsum[blockIdx.x] = buf[255];
}

__global__ void scan2_k(const int* __restrict__ bsum, int* __restrict__ boff, int nb) {
    __shared__ int buf[256];
    int tid = threadIdx.x;
    int v = (tid < nb) ? bsum[tid] : 0;
    buf[tid] = v;
    __syncthreads();
    for (int off = 1; off < 256; off <<= 1) {
        int t = (tid >= off) ? buf[tid - off] : 0;
        __syncthreads();
        buf[tid] += t;
        __syncthreads();
    }
    if (tid < nb) boff[tid] = buf[tid] - v;
}

__global__ void scan3_k(int* __restrict__ rowptr, const int* __restrict__ boff,
                        int N, int E) {
    int i = blockIdx.x * 256 + threadIdx.x;
    if (i < N) rowptr[i] += boff[blockIdx.x];
    if (i == 0) rowptr[N] = E;
}

// atomic-free fill: slot from deg pass, ushort scatter
__global__ void fill_k(const int* __restrict__ src, const int* __restrict__ dst,
                       const int* __restrict__ rowptr,
                       const unsigned short* __restrict__ slot16,
                       unsigned short* __restrict__ col16, int E) {
    int e = blockIdx.x * 256 + threadIdx.x;
    if (e >= E) return;
    int d = dst[e];
    col16[rowptr[d] + slot16[e]] = (unsigned short)src[e];
}

// ---------- MFMA GEMM (128 nodes/block) + fused el/er epilogue ----------
template <int KW, int M, int S, int HS, int HW>
__global__ void __launch_bounds__(256) gemm_k(const bf16* __restrict__ in,
                                              const void* __restrict__ W,
                                              const void* __restrict__ al,
                                              const void* __restrict__ ar,
                                              bf16* __restrict__ fs,
                                              float* __restrict__ el,
                                              float* __restrict__ er,
                                              const int* __restrict__ flag, int N) {
    constexpr int CT  = S / 16;
    constexpr int WST = 136;
    __shared__ short wlds[S * WST];
    const bool bf = (*flag != 0);
    const int tid = threadIdx.x;

    for (int idx = tid; idx < 64 * S; idx += 256) {
        int k2 = idx / S, p = idx % S;
        int j = p % HS, h = p / HS;
        int c = h * HW + j;
        bool valid = (j < HW);
        int k0 = 2 * k2;
        unsigned short u0 = (valid && k0 < KW)     ? w_bits(W, (size_t)k0 * M + c, bf)       : 0;
        unsigned short u1 = (valid && k0 + 1 < KW) ? w_bits(W, (size_t)(k0 + 1) * M + c, bf) : 0;
        *(unsigned*)&wlds[p * WST + 2 * k2] = (unsigned)u0 | ((unsigned)u1 << 16);
    }
    __syncthreads();

    const int wave = tid >> 6, lane = tid & 63;
    const int q = lane >> 4, l16 = lane & 15;
    const int base = blockIdx.x * 128;

    floatx4 acc[2][CT] = {};

#pragma unroll
    for (int chunk = 0; chunk < 4; ++chunk) {
        const int kb = chunk * 32 + q * 8;
        short8 a0 = {}, a1 = {};
        const int n0 = base + wave * 16 + l16;
        const int n1 = n0 + 64;
        if (n0 < N) a0 = *(const short8*)(in + (size_t)n0 * 128 + kb);
        if (n1 < N) a1 = *(const short8*)(in + (size_t)n1 * 128 + kb);
#pragma unroll
        for (int ct = 0; ct < CT; ++ct) {
            const int p = ct * 16 + l16;
            short8 b = *(const short8*)&wlds[p * WST + kb];
            acc[0][ct] = __builtin_amdgcn_mfma_f32_16x16x32_bf16(a0, b, acc[0][ct], 0, 0, 0);
            acc[1][ct] = __builtin_amdgcn_mfma_f32_16x16x32_bf16(a1, b, acc[1][ct], 0, 0, 0);
        }
    }

#pragma unroll
    for (int rt = 0; rt < 2; ++rt) {
        const int tb = base + rt * 64 + wave * 16;
#pragma unroll
        for (int ct = 0; ct < CT; ++ct) {
            const int p = ct * 16 + l16;
#pragma unroll
            for (int r = 0; r < 4; ++r) {
                int node = tb + q * 4 + r;
                if (node < N) fs[(size_t)node * S + p] = __float2bfloat16(acc[rt][ct][r]);
            }
        }
    }

    float* red = (float*)wlds;
#pragma unroll
    for (int rt = 0; rt < 2; ++rt) {
        __syncthreads();
        float elp[4][4] = {}, erp[4][4] = {};
#pragma unroll
        for (int ct = 0; ct < CT; ++ct) {
            const int p = ct * 16 + l16;
            const int j = p % HS, h = p / HS;
            const bool valid = (j < HW);
            float alc = valid ? ldx(al, h * HW + j, bf) : 0.f;
            float arc = valid ? ldx(ar, h * HW + j, bf) : 0.f;
#pragma unroll
            for (int r = 0; r < 4; ++r) {
                float v = acc[rt][ct][r];
#pragma unroll
                for (int h2 = 0; h2 < 4; ++h2) {
                    elp[r][h2] += (h == h2) ? v * alc : 0.f;
                    erp[r][h2] += (h == h2) ? v * arc : 0.f;
                }
            }
        }
#pragma unroll
        for (int r = 0; r < 4; ++r)
#pragma unroll
            for (int h2 = 0; h2 < 4; ++h2) {
                int slot = (wave * 128) + (q * 32) + (r * 8) + (h2 * 2);
                red[slot * 16 + l16] = elp[r][h2];
                red[(slot + 1) * 16 + l16] = erp[r][h2];
            }
        __syncthreads();
#pragma unroll
        for (int pass = 0; pass < 2; ++pass) {
            int slot = tid + pass * 256;
            float sum = 0.f;
#pragma unroll
            for (int j = 0; j < 16; ++j) sum += red[slot * 16 + j];
            int which = slot & 1;
            int h2 = (slot >> 1) & 3;
            int r  = (slot >> 3) & 3;
            int qq = (slot >> 5) & 3;
            int wv = slot >> 7;
            int node = base + rt * 64 + wv * 16 + qq * 4 + r;
            if (node < N) {
                if (which == 0) el[(size_t)node * 4 + h2] = sum;
                else            er[(size_t)node * 4 + h2] = sum;
            }
        }
    }
}

// ---------- wave-autonomous agg, layers 0/1 (S=128, HS=32) — R12 exact ----
// One wave per dst; 16-edge staged chunks (single stage sub-pass per lane),
// barrier-free gather: 4 groups x 16 lanes x 16B, lane strides 4, unroll 4.
template <bool RELU>
__global__ void __launch_bounds__(256) agg01_k(const float* __restrict__ el,
                                               const float* __restrict__ er,
                                               const bf16* __restrict__ fs,
                                               const int* __restrict__ rowptr,
                                               const unsigned short* __restrict__ col,
                                               bf16* __restrict__ out, int N) {
    const int wave = threadIdx.x >> 6, lane = threadIdx.x & 63;
    const int d = blockIdx.x * 4 + wave;
    __shared__ float wrow[4][16][4];
    __shared__ int   scol[4][16];
    if (d >= N) return;
    const int rs = rowptr[d], re = rowptr[d + 1];
    const int g = lane >> 4, lg = lane & 15;
    const int c0 = lg * 8;

    if (re == rs) {
        if (g == 0) *(uint4*)(out + (size_t)d * 128 + c0) = make_uint4(0, 0, 0, 0);
        return;
    }

    float4 er4 = *(const float4*)(er + (size_t)d * 4);
    float er_d[4] = {er4.x, er4.y, er4.z, er4.w};

    const int eh = lane >> 2;
    const int hh = lane & 3;
    const int h0 = lg >> 2;

    float acc[8] = {0, 0, 0, 0, 0, 0, 0, 0};
    float swp = 0.f;

    for (int cs = rs; cs < re; cs += 16) {
        int ne = min(16, re - cs);
        if (eh < ne) {
            int s = (int)col[cs + eh];
            if (hh == 0) scol[wave][eh] = s;
            float x = el[(size_t)s * 4 + hh] + er_d[hh];
            x = x >= 0.f ? x : 0.2f * x;
            float w = __expf(x);
            wrow[wave][eh][hh] = w;
            swp += w;
        }
#pragma unroll 4
        for (int e = g; e < ne; e += 4) {
            int s = scol[wave][e];
            float w = wrow[wave][e][h0];
            uint4 u = *(const uint4*)(fs + (size_t)s * 128 + c0);
            acc[0] += w * bl(u.x); acc[1] += w * bh(u.x);
            acc[2] += w * bl(u.y); acc[3] += w * bh(u.y);
            acc[4] += w * bl(u.z); acc[5] += w * bh(u.z);
            acc[6] += w * bl(u.w); acc[7] += w * bh(u.w);
        }
    }

#pragma unroll
    for (int k = 0; k < 8; ++k) {
        acc[k] += __shfl_xor(acc[k], 16);
        acc[k] += __shfl_xor(acc[k], 32);
    }
#pragma unroll
    for (int off = 4; off < 64; off <<= 1) swp += __shfl_xor(swp, off);
    float sh = __shfl(swp, h0);

    if (g == 0) {
        float inv = 1.0f / sh;
        float v[8];
#pragma unroll
        for (int k = 0; k < 8; ++k) {
            v[k] = acc[k] * inv;
            if (RELU) v[k] = fmaxf(v[k], 0.f);
        }
        uint4 o;
        o.x = (unsigned)f2b_bits(v[0]) | ((unsigned)f2b_bits(v[1]) << 16);
        o.y = (unsigned)f2b_bits(v[2]) | ((unsigned)f2b_bits(v[3]) << 16);
        o.z = (unsigned)f2b_bits(v[4]) | ((unsigned)f2b_bits(v[5]) << 16);
        o.w = (unsigned)f2b_bits(v[6]) | ((unsigned)f2b_bits(v[7]) << 16);
        *(uint4*)(out + (size_t)d * 128 + c0) = o;
    }
}

// ---------- layer-2 agg + fused head-mean + log_softmax -> d_out ----------
__global__ void __launch_bounds__(192) agg2_k(const float* __restrict__ el,
                                              const float* __restrict__ er,
                                              const bf16* __restrict__ fs,
                                              const int* __restrict__ rowptr,
                                              const unsigned short* __restrict__ col,
                                              void* __restrict__ out,
                                              const int* __restrict__ flag) {
    constexpr int HS = 48, S = 192, LPG = 24, TPB = 192;
    constexpr int NG = TPB / LPG;       // 8
    constexpr int CH = TPB / 4;         // 48
    constexpr int NW = TPB / 64;        // 3
    const int d = blockIdx.x;
    const int tid = threadIdx.x;
    const bool bf = (*flag != 0);
    const int rs = rowptr[d], re = rowptr[d + 1];

    __shared__ float wrow[CH][4];
    __shared__ int scol_s[CH];
    __shared__ float part[NG][S];
    __shared__ float red2[NW][4];
    __shared__ float sh_s[4];
    __shared__ float vout[S];

    if (re == rs) {
        if (tid < 47) {
            float r = -logf(47.f);
            if (bf) ((bf16*)out)[(size_t)d * 47 + tid] = __float2bfloat16(r);
            else    ((float*)out)[(size_t)d * 47 + tid] = r;
        }
        return;
    }

    float4 er4 = *(const float4*)(er + (size_t)d * 4);
    float er_d[4] = {er4.x, er4.y, er4.z, er4.w};

    const int g  = tid / LPG;
    const int lg = tid % LPG;
    const int c0 = lg * 8;
    const int h0 = c0 / HS;

    float acc[8] = {0, 0, 0, 0, 0, 0, 0, 0};
    float swpart = 0.f;

    for (int cs = rs; cs < re; cs += CH) {
        int ne = min(CH, re - cs);
        if (tid < ne * 4) {
            int j = tid >> 2, h = tid & 3;
            int s = (int)col[cs + j];
            if (h == 0) scol_s[j] = s;
            float x = el[(size_t)s * 4 + h] + er_d[h];
            x = x >= 0.f ? x : 0.2f * x;
            float w = __expf(x);
            wrow[j][h] = w;
            swpart += w;
        }
        __syncthreads();
#pragma unroll 4
        for (int e = g; e < ne; e += NG) {
            int s = scol_s[e];
            uint4 u = *(const uint4*)(fs + (size_t)s * S + c0);
            float w = wrow[e][h0];
            acc[0] += w * bl(u.x); acc[1] += w * bh(u.x);
            acc[2] += w * bl(u.y); acc[3] += w * bh(u.y);
            acc[4] += w * bl(u.z); acc[5] += w * bh(u.z);
            acc[6] += w * bl(u.w); acc[7] += w * bh(u.w);
        }
        __syncthreads();
    }

    float sw = swpart;
#pragma unroll
    for (int off = 4; off < 64; off <<= 1) sw += __shfl_xor(sw, off);
    const int wave = tid >> 6, lane = tid & 63;
    if (lane < 4) red2[wave][lane] = sw;
#pragma unroll
    for (int k = 0; k < 8; ++k) part[g][c0 + k] = acc[k];
    __syncthreads();
    if (tid < 4) {
        float s = 0.f;
#pragma unroll
        for (int w = 0; w < NW; ++w) s += red2[w][tid];
        sh_s[tid] = s;
    }
    __syncthreads();

    if (tid < S / 4) {
        int c = tid * 4;
        float4 v = make_float4(0, 0, 0, 0);
#pragma unroll
        for (int gg = 0; gg < NG; ++gg) {
            v.x += part[gg][c + 0]; v.y += part[gg][c + 1];
            v.z += part[gg][c + 2]; v.w += part[gg][c + 3];
        }
        float is = 1.0f / sh_s[c / HS];
        vout[c + 0] = v.x * is; vout[c + 1] = v.y * is;
        vout[c + 2] = v.z * is; vout[c + 3] = v.w * is;
    }
    __syncthreads();

    if (tid < 64) {
        int c = tid;
        float val = 0.f, vm = -INFINITY;
        if (c < 47) {
            val = 0.25f * (vout[c] + vout[48 + c] + vout[96 + c] + vout[144 + c]);
            vm = val;
        }
        float m = vm;
#pragma unroll
        for (int off = 32; off >= 1; off >>= 1) m = fmaxf(m, __shfl_xor(m, off));
        float ex = (c < 47) ? __expf(val - m) : 0.f;
        float s = ex;
#pragma unroll
        for (int off = 32; off >= 1; off >>= 1) s += __shfl_xor(s, off);
        if (c < 47) {
            float r = val - m - logf(s);
            if (bf) ((bf16*)out)[(size_t)d * 47 + c] = __float2bfloat16(r);
            else    ((float*)out)[(size_t)d * 47 + c] = r;
        }
    }
}

extern "C" void kernel_launch(void* const* d_in, const int* in_sizes, int n_in,
                              void* d_out, int out_size, void* d_ws, size_t ws_size,
                              hipStream_t stream) {
    const void* x   = d_in[0];
    const void* W0  = d_in[1];
    const void* al0 = d_in[2];
    const void* ar0 = d_in[3];
    const void* W1  = d_in[4];
    const void* al1 = d_in[5];
    const void* ar1 = d_in[6];
    const void* W2  = d_in[7];
    const void* al2 = d_in[8];
    const void* ar2 = d_in[9];
    const int* src  = (const int*)d_in[10];
    const int* dst  = (const int*)d_in[11];
    const int E = in_sizes[10];
    const int N = NN;

    bf16* fs    = (bf16*)d_ws;                      // N*192 bf16
    bf16* hb16  = fs + (size_t)N * 192;             // N*128 bf16
    bf16* xpad  = hb16 + (size_t)N * 128;           // N*128 bf16
    float* el   = (float*)(xpad + (size_t)N * 128); // N*4
    float* er   = el + (size_t)N * H;               // N*4
    int* rowptr = (int*)(er + (size_t)N * H);       // N+1
    int* deg    = rowptr + (N + 1);                 // N
    unsigned short* col16  = (unsigned short*)(deg + N);   // E u16
    unsigned short* slot16 = col16 + E;                    // E u16
    int* bsum   = (int*)(slot16 + E);               // 256
    int* boff   = bsum + 256;                       // 256
    int* flag   = boff + 256;                       // 1

    const int gN  = (N + 255) / 256;                // 196 blocks
    const int gE  = (E + 255) / 256;
    const int gG  = (N + 127) / 128;                // 391 gemm blocks
    const int gA  = (N + 3) / 4;                    // 12500 agg01 blocks

    detect_k<<<1, 256, 0, stream>>>(x, flag);
    xpad_k<<<(N * 128 + 255) / 256, 256, 0, stream>>>(x, xpad, flag, N * 128);

    // CSR build (graph identical for all 3 layers)
    hipMemsetAsync(deg, 0, (size_t)N * 4, stream);
    deg_k<<<gE, 256, 0, stream>>>(dst, deg, slot16, E);
    scan1_k<<<gN, 256, 0, stream>>>(deg, rowptr, bsum, N);
    scan2_k<<<1, 256, 0, stream>>>(bsum, boff, gN);
    scan3_k<<<gN, 256, 0, stream>>>(rowptr, boff, N, E);
    fill_k<<<gE, 256, 0, stream>>>(src, dst, rowptr, slot16, col16, E);

    // ---------------- Layer 0: W[100,128], HS=HW=32 ----------------
    gemm_k<100, 128, 128, 32, 32><<<gG, 256, 0, stream>>>(
        xpad, W0, al0, ar0, fs, el, er, flag, N);
    agg01_k<true><<<gA, 256, 0, stream>>>(el, er, fs, rowptr, col16, hb16, N);

    // ---------------- Layer 1: W[128,128], HS=HW=32 ----------------
    gemm_k<128, 128, 128, 32, 32><<<gG, 256, 0, stream>>>(
        hb16, W1, al1, ar1, fs, el, er, flag, N);
    agg01_k<true><<<gA, 256, 0, stream>>>(el, er, fs, rowptr, col16, hb16, N);

    // ---------------- Layer 2: W[128,188], HS=48, HW=47 (head-padded) ------
    gemm_k<128, 188, 192, 48, 47><<<gG, 256, 0, stream>>>(
        hb16, W2, al2, ar2, fs, el, er, flag, N);
    agg2_k<<<N, 192, 0, stream>>>(el, er, fs, rowptr, col16, d_out, flag);
}